// Round 2
// 588.753 us; speedup vs baseline: 1.0944x; 1.0944x over previous
//
#include <hip/hip_runtime.h>

// Conv2d(64->64, k=3, pad=1) + bias, fp32 NCHW 16x64x256x256.
// Round 4 (resubmit after infra failure — source unchanged):
//  - conv: weights register-resident per wave (1 m-tile/wave, 144 VGPR, loaded
//    once per block), 512-thread blocks walk 8 h-tiles with a 2-phase pipeline
//    (reg-staged next tile under compute, raw s_barriers, no vmcnt(0) drain),
//    B-fragment row reuse (48 ds_reads per wave-tile instead of 72).
//  - transpose: packed bf16-pair ds_write_b32 + chunk-XOR swizzle
//    (16-way bank conflicts -> ~4-way), read side applies the same XOR.

#define N_   16
#define C_   64
#define HW_  256
#define TH   8
#define TW   32
#define NPIX ((TH + 2) * (TW + 2))   // 340 staged pixels per tile
#define ICP  72                      // LDS pitch in bf16 (144 B)
#define NT   8                       // h-tiles per block (conv_mfma_wreg)

typedef __attribute__((ext_vector_type(8)))  short short8;   // 8 bf16 = 4 VGPRs
typedef __attribute__((ext_vector_type(16))) float f32x16;   // 32x32 acc

static __device__ __forceinline__ unsigned short f2bf(float f) {
    unsigned u = __builtin_bit_cast(unsigned, f);
    return (unsigned short)((u + 0x7fffu + ((u >> 16) & 1u)) >> 16);   // RNE
}

// ---- pass 0: W OIHW fp32 -> Wt[oc][tap][ic] bf16 ----
__global__ void repack_w_bf16(const float* __restrict__ W, unsigned short* __restrict__ Wt) {
    int i = blockIdx.x * 256 + threadIdx.x;          // 64*9*64 = 36864
    if (i < C_ * 9 * C_) {
        int ic = i & 63, tap = (i >> 6) % 9, oc = (i >> 6) / 9;
        Wt[i] = f2bf(W[(oc * C_ + ic) * 9 + tap]);
    }
}

// ---- pass 1: x fp32 NCHW -> xt bf16 NHWC ----
// Phase 1 writes bf16 PAIRS (b32) with an ic-chunk XOR swizzle by (w&7):
// 4-way worst-case bank conflict instead of the old ~16-way scalar u16 writes.
__global__ __launch_bounds__(256) void transpose_nhwc(const float* __restrict__ x,
                                                      unsigned short* __restrict__ xt) {
    __shared__ unsigned short st[64][ICP];           // 64w x 64ic tile (pitch 72)
    const int tid = threadIdx.x;
    const int w0  = blockIdx.x * 64;                 // 0..3
    const int h   = blockIdx.y;
    const int n   = blockIdx.z;

    const int seg = tid & 7;                         // float4 w-chunk within 32-w half
    const int icp = tid >> 3;                        // 0..31 ic-pair
    const int c   = icp >> 2, q = icp & 3;           // ic 8-chunk, pair-in-chunk

    #pragma unroll
    for (int k = 0; k < 2; ++k) {
        const float* p0 = x + (((size_t)(n * C_ + 2 * icp) * HW_ + h) * HW_ + w0 + k * 32 + seg * 4);
        float4 a = *(const float4*)p0;                       // ic = 2*icp
        float4 b = *(const float4*)(p0 + (size_t)HW_ * HW_); // ic = 2*icp+1
        unsigned pk0 = (unsigned)f2bf(a.x) | ((unsigned)f2bf(b.x) << 16);
        unsigned pk1 = (unsigned)f2bf(a.y) | ((unsigned)f2bf(b.y) << 16);
        unsigned pk2 = (unsigned)f2bf(a.z) | ((unsigned)f2bf(b.z) << 16);
        unsigned pk3 = (unsigned)f2bf(a.w) | ((unsigned)f2bf(b.w) << 16);
        const int wb = k * 32 + seg * 4;
        *(unsigned*)&st[wb + 0][(c ^ ((wb + 0) & 7)) * 8 + q * 2] = pk0;
        *(unsigned*)&st[wb + 1][(c ^ ((wb + 1) & 7)) * 8 + q * 2] = pk1;
        *(unsigned*)&st[wb + 2][(c ^ ((wb + 2) & 7)) * 8 + q * 2] = pk2;
        *(unsigned*)&st[wb + 3][(c ^ ((wb + 3) & 7)) * 8 + q * 2] = pk3;
    }
    __syncthreads();
    #pragma unroll
    for (int j = 0; j < 2; ++j) {
        int w = (tid >> 3) + 32 * j, eg = tid & 7;
        uint4 v = *(const uint4*)&st[w][(eg ^ (w & 7)) * 8];  // undo swizzle
        *(uint4*)(xt + (((size_t)n * HW_ + h) * HW_ + w0 + w) * C_ + eg * 8) = v;
    }
}

// ---- pass 2: MFMA implicit GEMM, register-resident weights, h-walking tiles ----
__global__ __launch_bounds__(512, 2) void conv_mfma_wreg(const unsigned short* __restrict__ xt,
                                                         const unsigned short* __restrict__ Wt,
                                                         const float* __restrict__ bias,
                                                         float* __restrict__ out) {
    __shared__ unsigned short sx[NPIX][ICP];         // 340*72*2 = 48960 B

    const int tid  = threadIdx.x;
    const int L    = tid & 63, wv = tid >> 6;        // 8 waves
    const int half = L >> 5,  lm = L & 31;
    const int mg   = wv >> 2;                        // m-group: oc 32*mg..+32
    const int ng   = wv & 3;                         // n-group: rows 2*ng, 2*ng+1

    const int bx = blockIdx.x;                       // 512 blocks
    const int wt = bx & 7, hg = (bx >> 3) & 3, n = bx >> 5;
    const int w0 = wt * TW;

    // ---- weights: 36 frags (this wave's 32-oc slice), register-resident ----
    short8 wf[9][4];
    {
        const unsigned short* wbase = Wt + (size_t)(32 * mg + lm) * 576 + half * 8;
        #pragma unroll
        for (int tap = 0; tap < 9; ++tap)
            #pragma unroll
            for (int s = 0; s < 4; ++s)
                wf[tap][s] = __builtin_bit_cast(short8, *(const uint4*)(wbase + tap * 64 + s * 16));
    }
    // bias in C-fragment order (oc = 32*mg + (r&3)+8*(r>>2)+4*half)
    f32x16 bias_v;
    #pragma unroll
    for (int r = 0; r < 16; ++r) {
        int ro = (r & 3) + 8 * (r >> 2) + 4 * half;
        bias_v[r] = bias[32 * mg + ro];
    }

    const unsigned short* xtn = xt + (size_t)n * HW_ * HW_ * C_;
    float* outn = out + (size_t)n * C_ * HW_ * HW_;
    const unsigned short* pB = &sx[2 * ng * 34 + lm][half * 8];

    // ---- prologue: stage tile 0 ----
    {
        const int h0 = hg * (NT * TH);
        #pragma unroll
        for (int k = 0; k < 6; ++k) {
            int i = tid + k * 512;                   // 16B chunks: 340 px * 8
            if (i < NPIX * 8) {
                int p = i >> 3, e = i & 7;
                int r = p / 34, col = p - r * 34;
                int gh = h0 + r - 1, gw = w0 + col - 1;
                uint4 v = make_uint4(0, 0, 0, 0);
                if ((unsigned)gh < HW_ && (unsigned)gw < HW_)
                    v = *(const uint4*)(xtn + ((size_t)gh * HW_ + gw) * C_ + e * 8);
                *(uint4*)&sx[p][e * 8] = v;
            }
        }
    }
    asm volatile("s_waitcnt lgkmcnt(0)" ::: "memory");
    __builtin_amdgcn_sched_barrier(0);
    __builtin_amdgcn_s_barrier();
    __builtin_amdgcn_sched_barrier(0);

    for (int t = 0; t < NT; ++t) {
        const int h0 = hg * (NT * TH) + t * TH;

        // ---- issue next-tile loads to regs (latency hides under compute) ----
        uint4 stg[6];
        if (t < NT - 1) {
            const int h1 = h0 + TH;
            #pragma unroll
            for (int k = 0; k < 6; ++k) {
                int i = tid + k * 512;
                stg[k] = make_uint4(0, 0, 0, 0);
                if (i < NPIX * 8) {
                    int p = i >> 3, e = i & 7;
                    int r = p / 34, col = p - r * 34;
                    int gh = h1 + r - 1, gw = w0 + col - 1;
                    if ((unsigned)gh < HW_ && (unsigned)gw < HW_)
                        stg[k] = *(const uint4*)(xtn + ((size_t)gh * HW_ + gw) * C_ + e * 8);
                }
            }
        }

        // ---- compute tile t: rows 2ng..2ng+3 loaded once per (kw,s), feed both accs ----
        f32x16 acc0 = bias_v, acc1 = bias_v;
        #pragma unroll
        for (int kw = 0; kw < 3; ++kw) {
            #pragma unroll
            for (int s = 0; s < 4; ++s) {
                short8 q0 = __builtin_bit_cast(short8, *(const uint4*)(pB + (0 * 34 + kw) * ICP + s * 16));
                short8 q1 = __builtin_bit_cast(short8, *(const uint4*)(pB + (1 * 34 + kw) * ICP + s * 16));
                short8 q2 = __builtin_bit_cast(short8, *(const uint4*)(pB + (2 * 34 + kw) * ICP + s * 16));
                short8 q3 = __builtin_bit_cast(short8, *(const uint4*)(pB + (3 * 34 + kw) * ICP + s * 16));
                acc0 = __builtin_amdgcn_mfma_f32_32x32x16_bf16(wf[0 * 3 + kw][s], q0, acc0, 0, 0, 0);
                acc1 = __builtin_amdgcn_mfma_f32_32x32x16_bf16(wf[0 * 3 + kw][s], q1, acc1, 0, 0, 0);
                acc0 = __builtin_amdgcn_mfma_f32_32x32x16_bf16(wf[1 * 3 + kw][s], q1, acc0, 0, 0, 0);
                acc1 = __builtin_amdgcn_mfma_f32_32x32x16_bf16(wf[1 * 3 + kw][s], q2, acc1, 0, 0, 0);
                acc0 = __builtin_amdgcn_mfma_f32_32x32x16_bf16(wf[2 * 3 + kw][s], q2, acc0, 0, 0, 0);
                acc1 = __builtin_amdgcn_mfma_f32_32x32x16_bf16(wf[2 * 3 + kw][s], q3, acc1, 0, 0, 0);
            }
        }

        // ---- stores (async drain; never vmcnt(0)-waited) ----
        const int row0 = h0 + 2 * ng;
        #pragma unroll
        for (int r = 0; r < 16; ++r) {
            int ro = (r & 3) + 8 * (r >> 2) + 4 * half;
            size_t base = ((size_t)(32 * mg + ro) * HW_ + row0) * HW_ + w0 + lm;
            outn[base]       = acc0[r];
            outn[base + HW_] = acc1[r];
        }

        if (t < NT - 1) {
            __builtin_amdgcn_sched_barrier(0);
            __builtin_amdgcn_s_barrier();            // A: all waves done reading tile t
            __builtin_amdgcn_sched_barrier(0);
            #pragma unroll
            for (int k = 0; k < 6; ++k) {            // compiler emits counted vmcnt for stg
                int i = tid + k * 512;
                if (i < NPIX * 8) {
                    int p = i >> 3, e = i & 7;
                    *(uint4*)&sx[p][e * 8] = stg[k];
                }
            }
            asm volatile("s_waitcnt lgkmcnt(0)" ::: "memory");
            __builtin_amdgcn_sched_barrier(0);
            __builtin_amdgcn_s_barrier();            // B: tile t+1 visible
            __builtin_amdgcn_sched_barrier(0);
        }
    }
}

// ---- fallback: fp32 NCHW source, scalar transpose staging (small-ws path) ----
__global__ __launch_bounds__(256, 3) void conv_mfma_f32src(const float* __restrict__ x,
                                                           const unsigned short* __restrict__ Wt,
                                                           const float* __restrict__ bias,
                                                           float* __restrict__ out) {
    __shared__ unsigned short sx[NPIX][ICP];
    const int tid  = threadIdx.x;
    const int L    = tid & 63, wv = tid >> 6;
    const int half = L >> 5,  lm = L & 31;
    const int w0 = blockIdx.x * TW, h0 = blockIdx.y * TH, n = blockIdx.z;

    f32x16 acc00, acc01, acc10, acc11;
    #pragma unroll
    for (int r = 0; r < 16; ++r) {
        int ro = (r & 3) + 8 * (r >> 2) + 4 * half;
        float b0 = bias[ro], b1 = bias[32 + ro];
        acc00[r] = b0; acc01[r] = b0;
        acc10[r] = b1; acc11[r] = b1;
    }

    const float* xn = x + (size_t)n * C_ * HW_ * HW_;
    for (int c = tid; c < NPIX * 32; c += 256) {
        int icp = c / NPIX;
        int p   = c - icp * NPIX;
        int ph  = p / 34;
        int gh  = h0 + ph - 1, gw = w0 + (p - ph * 34) - 1;
        float v0 = 0.f, v1 = 0.f;
        if ((unsigned)gh < HW_ && (unsigned)gw < HW_) {
            const float* px = xn + ((size_t)(icp * 2) * HW_ + gh) * HW_ + gw;
            v0 = px[0];
            v1 = px[HW_ * HW_];
        }
        unsigned pk = (unsigned)f2bf(v0) | ((unsigned)f2bf(v1) << 16);
        *(unsigned*)&sx[p][icp * 2] = pk;
    }
    __syncthreads();

    const int r0 = 2 * wv;
    const unsigned short* wr0 = Wt + (0 * 32 + lm) * 576;
    const unsigned short* wr1 = Wt + (1 * 32 + lm) * 576;
    #pragma unroll
    for (int kh = 0; kh < 3; ++kh) {
        #pragma unroll
        for (int kw = 0; kw < 3; ++kw) {
            const int tap = kh * 3 + kw;
            const unsigned short* a0p = wr0 + tap * 64;
            const unsigned short* a1p = wr1 + tap * 64;
            const unsigned short* b0p = &sx[(r0 + kh) * 34 + lm + kw][0];
            const unsigned short* b1p = &sx[(r0 + 1 + kh) * 34 + lm + kw][0];
            #pragma unroll
            for (int s = 0; s < 4; ++s) {
                const int eo = s * 16 + half * 8;
                short8 a0 = __builtin_bit_cast(short8, *(const uint4*)(a0p + eo));
                short8 a1 = __builtin_bit_cast(short8, *(const uint4*)(a1p + eo));
                short8 b0 = __builtin_bit_cast(short8, *(const uint4*)(b0p + eo));
                short8 b1 = __builtin_bit_cast(short8, *(const uint4*)(b1p + eo));
                acc00 = __builtin_amdgcn_mfma_f32_32x32x16_bf16(a0, b0, acc00, 0, 0, 0);
                acc01 = __builtin_amdgcn_mfma_f32_32x32x16_bf16(a0, b1, acc01, 0, 0, 0);
                acc10 = __builtin_amdgcn_mfma_f32_32x32x16_bf16(a1, b0, acc10, 0, 0, 0);
                acc11 = __builtin_amdgcn_mfma_f32_32x32x16_bf16(a1, b1, acc11, 0, 0, 0);
            }
        }
    }

    float* outn = out + (size_t)n * C_ * HW_ * HW_;
    #pragma unroll
    for (int r = 0; r < 16; ++r) {
        int ro = (r & 3) + 8 * (r >> 2) + 4 * half;
        size_t base0 = ((size_t)ro        * HW_ + (h0 + r0)) * HW_ + w0 + lm;
        size_t base1 = ((size_t)(32 + ro) * HW_ + (h0 + r0)) * HW_ + w0 + lm;
        outn[base0]       = acc00[r];
        outn[base0 + HW_] = acc01[r];
        outn[base1]       = acc10[r];
        outn[base1 + HW_] = acc11[r];
    }
}

extern "C" void kernel_launch(void* const* d_in, const int* in_sizes, int n_in,
                              void* d_out, int out_size, void* d_ws, size_t ws_size,
                              hipStream_t stream) {
    const float* x = (const float*)d_in[0];
    const float* W = (const float*)d_in[1];
    const float* b = (const float*)d_in[2];
    float* out = (float*)d_out;

    const size_t xt_bytes = (size_t)N_ * HW_ * HW_ * C_ * sizeof(unsigned short);  // 128 MiB
    const size_t wt_bytes = (size_t)C_ * 9 * C_ * sizeof(unsigned short);          // 72 KiB

    if (ws_size >= xt_bytes + wt_bytes) {
        unsigned short* xt = (unsigned short*)d_ws;
        unsigned short* Wt = (unsigned short*)d_ws + xt_bytes / 2;
        repack_w_bf16<<<(C_ * 9 * C_ + 255) / 256, 256, 0, stream>>>(W, Wt);
        transpose_nhwc<<<dim3(4, HW_, N_), 256, 0, stream>>>(x, xt);
        // 512 blocks: n(16) x h-group(4) x w-tile(8); each walks NT=8 h-tiles
        conv_mfma_wreg<<<dim3(512), dim3(512), 0, stream>>>(xt, Wt, b, out);
    } else if (ws_size >= wt_bytes) {
        unsigned short* Wt = (unsigned short*)d_ws;
        repack_w_bf16<<<(C_ * 9 * C_ + 255) / 256, 256, 0, stream>>>(W, Wt);
        conv_mfma_f32src<<<dim3(HW_ / TW, HW_ / TH, N_), 256, 0, stream>>>(x, Wt, b, out);
    }
}